// Round 7
// baseline (382.175 us; speedup 1.0000x reference)
//
#include <hip/hip_runtime.h>
#include <hip/hip_bf16.h>

#define BN_EPS 1e-5f
#define NB 64
#define NN 1000
#define NP 1024
#define HD 128
#define CS 8
#define NC 125  // NN/CS exactly

// ---------------------------------------------------------------------------
// Embedding MLP, register-tiled. 64 nodes/block, 256 threads.
// ---------------------------------------------------------------------------
__global__ __launch_bounds__(256) void k_embed(
    const float* __restrict__ locs,
    const float* __restrict__ W0, const float* __restrict__ b0,
    const float* __restrict__ W1, const float* __restrict__ b1,
    const float* __restrict__ g1, const float* __restrict__ be1,
    const float* __restrict__ m1, const float* __restrict__ v1,
    const float* __restrict__ Wo, const float* __restrict__ bo,
    float* __restrict__ x) {
  __shared__ float z1T[64][68];
  __shared__ float z2T[64][68];
  int tid = threadIdx.x;
  long base = (long)blockIdx.x * 64;

  // ---- phase A ----
  {
    int d = tid & 63;
    int q = tid >> 6;  // wave id 0..3
    float w0x = W0[d], w0y = W0[64 + d], bb = b0[d];
#pragma unroll
    for (int g = 0; g < 4; ++g) {
      float vv[4];
#pragma unroll
      for (int i = 0; i < 4; ++i) {
        int n = g * 16 + q * 4 + i;
        float lx = locs[(base + n) * 2 + 0];
        float ly = locs[(base + n) * 2 + 1];
        vv[i] = fmaxf(fmaf(lx, w0x, fmaf(ly, w0y, bb)), 0.f);
      }
      float4 v = make_float4(vv[0], vv[1], vv[2], vv[3]);
      *(float4*)&z1T[d][g * 16 + q * 4] = v;
    }
  }
  __syncthreads();

  int nt = tid & 15;   // nodes 4nt..4nt+3
  int dt = tid >> 4;   // dims 4dt..4dt+3 (and +64 in phase C)

  // ---- phase B ----
  {
    float acc[4][4];
#pragma unroll
    for (int i = 0; i < 4; ++i)
#pragma unroll
      for (int j = 0; j < 4; ++j) acc[i][j] = 0.f;
#pragma unroll 4
    for (int k = 0; k < 64; ++k) {
      float4 zv = *(const float4*)&z1T[k][4 * nt];
      float4 wv = *(const float4*)&W1[k * 64 + 4 * dt];
      float zz[4] = {zv.x, zv.y, zv.z, zv.w};
      float ww[4] = {wv.x, wv.y, wv.z, wv.w};
#pragma unroll
      for (int i = 0; i < 4; ++i)
#pragma unroll
        for (int j = 0; j < 4; ++j)
          acc[i][j] = fmaf(zz[i], ww[j], acc[i][j]);
    }
    float4 b1v = *(const float4*)&b1[4 * dt];
    float4 g1v = *(const float4*)&g1[4 * dt];
    float4 bev = *(const float4*)&be1[4 * dt];
    float4 m1v = *(const float4*)&m1[4 * dt];
    float4 v1v = *(const float4*)&v1[4 * dt];
    float bbv[4] = {b1v.x, b1v.y, b1v.z, b1v.w};
    float ggv[4] = {g1v.x, g1v.y, g1v.z, g1v.w};
    float eev[4] = {bev.x, bev.y, bev.z, bev.w};
    float mmv[4] = {m1v.x, m1v.y, m1v.z, m1v.w};
    float vvv[4] = {v1v.x, v1v.y, v1v.z, v1v.w};
#pragma unroll
    for (int j = 0; j < 4; ++j) {
      float sc = ggv[j] * rsqrtf(vvv[j] + BN_EPS);
      float sh = eev[j] - mmv[j] * sc;
      float o[4];
#pragma unroll
      for (int i = 0; i < 4; ++i)
        o[i] = fmaxf(fmaf(acc[i][j] + bbv[j], sc, sh), 0.f);
      *(float4*)&z2T[4 * dt + j][4 * nt] = make_float4(o[0], o[1], o[2], o[3]);
    }
  }
  __syncthreads();

  // ---- phase C ----
  {
    float acc[4][8];
#pragma unroll
    for (int i = 0; i < 4; ++i)
#pragma unroll
      for (int j = 0; j < 8; ++j) acc[i][j] = 0.f;
#pragma unroll 2
    for (int k = 0; k < 64; ++k) {
      float4 zv = *(const float4*)&z2T[k][4 * nt];
      float4 wa = *(const float4*)&Wo[k * 128 + 4 * dt];
      float4 wb = *(const float4*)&Wo[k * 128 + 64 + 4 * dt];
      float zz[4] = {zv.x, zv.y, zv.z, zv.w};
      float w0[4] = {wa.x, wa.y, wa.z, wa.w};
      float w1[4] = {wb.x, wb.y, wb.z, wb.w};
#pragma unroll
      for (int i = 0; i < 4; ++i) {
#pragma unroll
        for (int j = 0; j < 4; ++j) {
          acc[i][j] = fmaf(zz[i], w0[j], acc[i][j]);
          acc[i][4 + j] = fmaf(zz[i], w1[j], acc[i][4 + j]);
        }
      }
    }
    float4 bo0 = *(const float4*)&bo[4 * dt];
    float4 bo1 = *(const float4*)&bo[64 + 4 * dt];
#pragma unroll
    for (int i = 0; i < 4; ++i) {
      float4 o0 = make_float4(acc[i][0] + bo0.x, acc[i][1] + bo0.y,
                              acc[i][2] + bo0.z, acc[i][3] + bo0.w);
      float4 o1 = make_float4(acc[i][4] + bo1.x, acc[i][5] + bo1.y,
                              acc[i][6] + bo1.z, acc[i][7] + bo1.w);
      *(float4*)&x[(base + 4 * nt + i) * 128 + 4 * dt] = o0;
      *(float4*)&x[(base + 4 * nt + i) * 128 + 64 + 4 * dt] = o1;
    }
  }
}

// ---------------------------------------------------------------------------
// h = x @ W (64 rows/block, register-tiled 4x8) fused with e_src/e_dst dots.
// x tile staged in LDS with XOR-swizzled float4 slots:
//   slot_stored(row, col4) = col4 ^ ((row>>2)&7), flat stride 128 floats.
// Inner loop processes 4 k's per iteration via ds_read_b128 (conflict-free:
// 16 node-lanes map to 8 bank-groups, 2-way = free).
// ---------------------------------------------------------------------------
__global__ __launch_bounds__(256) void k_gemm_e(
    const float* __restrict__ x, const float* __restrict__ W,
    const float* __restrict__ asrc, const float* __restrict__ adst,
    float* __restrict__ h, float* __restrict__ es, float* __restrict__ ed) {
  __shared__ float xs[64 * 128];
  __shared__ float red[4][64][2];
  int tid = threadIdx.x;
  long base = (long)blockIdx.x * 64;

  // stage x tile, swizzled
#pragma unroll
  for (int p = 0; p < 8; ++p) {
    int idx = p * 1024 + tid * 4;
    int row = idx >> 7, col = idx & 127;
    int slot = (col >> 2) ^ ((row >> 2) & 7);
    float4 v = *(const float4*)&x[(base + row) * 128 + col];
    *(float4*)&xs[row * 128 + slot * 4] = v;
  }
  __syncthreads();

  int nt = tid & 15, dt = tid >> 4;
  int sw = nt & 7;
  float acc[4][8];
#pragma unroll
  for (int i = 0; i < 4; ++i)
#pragma unroll
    for (int j = 0; j < 8; ++j) acc[i][j] = 0.f;

#pragma unroll 2
  for (int k4 = 0; k4 < 32; ++k4) {
    int slot = (k4 ^ sw) * 4;
    float4 xv[4];
#pragma unroll
    for (int i = 0; i < 4; ++i)
      xv[i] = *(const float4*)&xs[(4 * nt + i) * 128 + slot];
#pragma unroll
    for (int kk = 0; kk < 4; ++kk) {
      int k = 4 * k4 + kk;
      float4 wa = *(const float4*)&W[k * 128 + 4 * dt];
      float4 wb = *(const float4*)&W[k * 128 + 64 + 4 * dt];
      float w0[4] = {wa.x, wa.y, wa.z, wa.w};
      float w1[4] = {wb.x, wb.y, wb.z, wb.w};
      float zz[4] = {xv[0].x, xv[1].x, xv[2].x, xv[3].x};
      if (kk == 1) { zz[0] = xv[0].y; zz[1] = xv[1].y; zz[2] = xv[2].y; zz[3] = xv[3].y; }
      if (kk == 2) { zz[0] = xv[0].z; zz[1] = xv[1].z; zz[2] = xv[2].z; zz[3] = xv[3].z; }
      if (kk == 3) { zz[0] = xv[0].w; zz[1] = xv[1].w; zz[2] = xv[2].w; zz[3] = xv[3].w; }
#pragma unroll
      for (int i = 0; i < 4; ++i) {
#pragma unroll
        for (int j = 0; j < 4; ++j) {
          acc[i][j] = fmaf(zz[i], w0[j], acc[i][j]);
          acc[i][4 + j] = fmaf(zz[i], w1[j], acc[i][4 + j]);
        }
      }
    }
  }

  // epilogue: store h, per-row e partials
  float4 as0 = *(const float4*)&asrc[4 * dt];
  float4 as1 = *(const float4*)&asrc[64 + 4 * dt];
  float4 ad0 = *(const float4*)&adst[4 * dt];
  float4 ad1 = *(const float4*)&adst[64 + 4 * dt];
  float ps[4], pd[4];
#pragma unroll
  for (int i = 0; i < 4; ++i) {
    float4 o0 = make_float4(acc[i][0], acc[i][1], acc[i][2], acc[i][3]);
    float4 o1 = make_float4(acc[i][4], acc[i][5], acc[i][6], acc[i][7]);
    *(float4*)&h[(base + 4 * nt + i) * 128 + 4 * dt] = o0;
    *(float4*)&h[(base + 4 * nt + i) * 128 + 64 + 4 * dt] = o1;
    ps[i] = o0.x * as0.x + o0.y * as0.y + o0.z * as0.z + o0.w * as0.w +
            o1.x * as1.x + o1.y * as1.y + o1.z * as1.z + o1.w * as1.w;
    pd[i] = o0.x * ad0.x + o0.y * ad0.y + o0.z * ad0.z + o0.w * ad0.w +
            o1.x * ad1.x + o1.y * ad1.y + o1.z * ad1.z + o1.w * ad1.w;
  }
#pragma unroll
  for (int i = 0; i < 4; ++i) {
    ps[i] += __shfl_xor(ps[i], 16, 64);
    ps[i] += __shfl_xor(ps[i], 32, 64);
    pd[i] += __shfl_xor(pd[i], 16, 64);
    pd[i] += __shfl_xor(pd[i], 32, 64);
  }
  int w = tid >> 6, lane = tid & 63;
  if (lane < 16) {
#pragma unroll
    for (int i = 0; i < 4; ++i) {
      red[w][4 * lane + i][0] = ps[i];
      red[w][4 * lane + i][1] = pd[i];
    }
  }
  __syncthreads();
  if (tid < 64) {
    float s = red[0][tid][0] + red[1][tid][0] + red[2][tid][0] + red[3][tid][0];
    float dd = red[0][tid][1] + red[1][tid][1] + red[2][tid][1] + red[3][tid][1];
    es[base + tid] = s;
    ed[base + tid] = dd;
  }
}

// ---------------------------------------------------------------------------
// Per batch: sort s (asc, with perm), e1/e2 prefix scan, per-target coeffs.
// ---------------------------------------------------------------------------
__global__ __launch_bounds__(256) void k_sort(
    const float* __restrict__ es, const float* __restrict__ ed,
    float* __restrict__ e1s, float* __restrict__ e2s, int* __restrict__ perm,
    int* __restrict__ kcut, float* __restrict__ alpha,
    float* __restrict__ beta) {
  __shared__ float ss[NP];
  __shared__ int id[NP];
  __shared__ float2 sa[NP];
  __shared__ float2 sb[NP];
  int tid = threadIdx.x, b = blockIdx.x;
  for (int i = tid; i < NP; i += 256) {
    ss[i] = (i < NN) ? es[b * NN + i] : INFINITY;
    id[i] = i;
  }
  for (int k = 2; k <= NP; k <<= 1) {
    for (int j = k >> 1; j > 0; j >>= 1) {
      __syncthreads();
      for (int i = tid; i < NP; i += 256) {
        int ixj = i ^ j;
        if (ixj > i) {
          bool up = ((i & k) == 0);
          float a = ss[i], c = ss[ixj];
          if ((a > c) == up) {
            ss[i] = c; ss[ixj] = a;
            int p = id[i]; id[i] = id[ixj]; id[ixj] = p;
          }
        }
      }
    }
  }
  __syncthreads();
  for (int i = tid; i < NP; i += 256) {
    float e1 = 0.f, e2 = 0.f;
    if (i < NN) {
      float s = ss[i];
      e1 = __expf(s);
      e2 = __expf(0.2f * s);
      e1s[b * NN + i] = e1;
      e2s[b * NN + i] = e2;
      perm[b * NN + i] = id[i];
    }
    sa[i] = make_float2(e1, e2);
  }
  __syncthreads();
  float2* src = sa;
  float2* dst = sb;
  for (int off = 1; off < NP; off <<= 1) {
    for (int i = tid; i < NP; i += 256) {
      float2 v = src[i];
      if (i >= off) {
        float2 u = src[i - off];
        v.x += u.x;
        v.y += u.y;
      }
      dst[i] = v;
    }
    __syncthreads();
    float2* t = src; src = dst; dst = t;
  }
  float s1tot = src[NN - 1].x;
  for (int i = tid; i < NN; i += 256) {
    float t = -ed[b * NN + i];
    int lo = 0, hi = NP;
    while (lo < hi) {
      int mid = (lo + hi) >> 1;
      if (ss[mid] <= t) lo = mid + 1; else hi = mid;
    }
    int k = lo;
    float p1 = (k > 0) ? src[k - 1].x : 0.f;
    float p2 = (k > 0) ? src[k - 1].y : 0.f;
    float Ed = __expf(-t);
    float Ed2 = __expf(-0.2f * t);
    float den = fmaf(Ed, s1tot - p1, Ed2 * p2);
    kcut[b * NN + i] = k;
    alpha[b * NN + i] = Ed / den;
    beta[b * NN + i] = Ed2 / den;
  }
}

// ---------------------------------------------------------------------------
// Per-chunk (8 sorted sources) weighted sums V1/V2 over dims.
// ---------------------------------------------------------------------------
__global__ __launch_bounds__(128) void k_chunk(
    const float* __restrict__ h, const float* __restrict__ e1s,
    const float* __restrict__ e2s, const int* __restrict__ perm,
    float* __restrict__ C1, float* __restrict__ C2) {
  int d = threadIdx.x, b = blockIdx.x, g = blockIdx.y;
  int c0 = g * 16, c1 = min(c0 + 16, NC);
  for (int c = c0; c < c1; ++c) {
    float v1 = 0.f, v2 = 0.f;
#pragma unroll
    for (int u = 0; u < CS; ++u) {
      int j = c * CS + u;
      int p = perm[b * NN + j];
      float hv = h[((long)b * NN + p) * HD + d];
      v1 = fmaf(e1s[b * NN + j], hv, v1);
      v2 = fmaf(e2s[b * NN + j], hv, v2);
    }
    C1[((long)b * (NC + 1) + c) * HD + d] = v1;
    C2[((long)b * (NC + 1) + c) * HD + d] = v2;
  }
}

// ---------------------------------------------------------------------------
// In-place exclusive prefix over chunks; slot NC receives totals.
// ---------------------------------------------------------------------------
__global__ __launch_bounds__(128) void k_cprefix(float* __restrict__ C1,
                                                 float* __restrict__ C2) {
  int d = threadIdx.x, b = blockIdx.x;
  float r1 = 0.f, r2 = 0.f;
  for (int c = 0; c < NC; ++c) {
    long o = ((long)b * (NC + 1) + c) * HD + d;
    float v1 = C1[o], v2 = C2[o];
    C1[o] = r1;
    C2[o] = r2;
    r1 += v1;
    r2 += v2;
  }
  long o = ((long)b * (NC + 1) + NC) * HD + d;
  C1[o] = r1;
  C2[o] = r2;
}

// ---------------------------------------------------------------------------
// out[i] = alpha_i*(T1 - C1[c_i] - partial1) + beta_i*(C2[c_i] + partial2)
// ---------------------------------------------------------------------------
template <bool APPLY_BN>
__global__ __launch_bounds__(128) void k_out(
    const float* __restrict__ h, const float* __restrict__ C1,
    const float* __restrict__ C2, const float* __restrict__ e1s,
    const float* __restrict__ e2s, const int* __restrict__ perm,
    const int* __restrict__ kcut, const float* __restrict__ alpha,
    const float* __restrict__ beta, const float* __restrict__ bias,
    const float* __restrict__ bng, const float* __restrict__ bnb,
    const float* __restrict__ bnm, const float* __restrict__ bnv,
    float* __restrict__ xo) {
  int d = threadIdx.x, b = blockIdx.x;
  int i0 = blockIdx.y * 8;
  float T1 = C1[((long)b * (NC + 1) + NC) * HD + d];
  float bs = bias[d];
  float sc = 0.f, sh = 0.f;
  if (APPLY_BN) {
    float g = bng[d], bb = bnb[d], m = bnm[d], v = bnv[d];
    sc = g * rsqrtf(v + BN_EPS);
    sh = bb - m * sc;
  }
  for (int i = i0; i < i0 + 8; ++i) {
    int k = kcut[b * NN + i];
    float al = alpha[b * NN + i], bt = beta[b * NN + i];
    int c = k >> 3;
    float base1 = C1[((long)b * (NC + 1) + c) * HD + d];
    float base2 = C2[((long)b * (NC + 1) + c) * HD + d];
    float p1 = 0.f, p2 = 0.f;
    for (int j = c * CS; j < k; ++j) {
      int p = perm[b * NN + j];
      float hv = h[((long)b * NN + p) * HD + d];
      p1 = fmaf(e1s[b * NN + j], hv, p1);
      p2 = fmaf(e2s[b * NN + j], hv, p2);
    }
    float val = fmaf(al, T1 - base1 - p1, fmaf(bt, base2 + p2, bs));
    long off = ((long)b * NN + i) * HD + d;
    xo[off] = APPLY_BN ? fmaxf(fmaf(val, sc, sh), 0.f) : val;
  }
}

extern "C" void kernel_launch(void* const* d_in, const int* in_sizes, int n_in,
                              void* d_out, int out_size, void* d_ws,
                              size_t ws_size, hipStream_t stream) {
  const float* locs = (const float*)d_in[0];
  const float* le_W0 = (const float*)d_in[1];
  const float* le_b0 = (const float*)d_in[2];
  const float* le_W1 = (const float*)d_in[3];
  const float* le_b1 = (const float*)d_in[4];
  const float* le_bn_g = (const float*)d_in[5];
  const float* le_bn_b = (const float*)d_in[6];
  const float* le_bn_m = (const float*)d_in[7];
  const float* le_bn_v = (const float*)d_in[8];
  const float* le_Wo = (const float*)d_in[9];
  const float* le_bo = (const float*)d_in[10];
  const float* gat_W = (const float*)d_in[11];
  const float* gat_asrc = (const float*)d_in[12];
  const float* gat_adst = (const float*)d_in[13];
  const float* gat_b = (const float*)d_in[14];
  const float* bn_g = (const float*)d_in[15];
  const float* bn_b = (const float*)d_in[16];
  const float* bn_m = (const float*)d_in[17];
  const float* bn_v = (const float*)d_in[18];

  float* x = (float*)d_out;
  float* h = (float*)d_ws;                 // 8,192,000
  float* C1 = h + 8192000;                 // 1,032,192
  float* C2 = C1 + 1032192;                // 1,032,192
  float* es = C2 + 1032192;
  float* ed = es + 64000;
  float* e1s = ed + 64000;
  float* e2s = e1s + 64000;
  float* alpha = e2s + 64000;
  float* beta = alpha + 64000;
  int* perm = (int*)(beta + 64000);
  int* kcut = perm + 64000;

  k_embed<<<1000, 256, 0, stream>>>(locs, le_W0, le_b0, le_W1, le_b1, le_bn_g,
                                    le_bn_b, le_bn_m, le_bn_v, le_Wo, le_bo,
                                    x);
  for (int l = 0; l < 3; ++l) {
    k_gemm_e<<<1000, 256, 0, stream>>>(x, gat_W + l * 128 * 128,
                                       gat_asrc + l * 128, gat_adst + l * 128,
                                       h, es, ed);
    k_sort<<<NB, 256, 0, stream>>>(es, ed, e1s, e2s, perm, kcut, alpha, beta);
    k_chunk<<<dim3(NB, 8), 128, 0, stream>>>(h, e1s, e2s, perm, C1, C2);
    k_cprefix<<<NB, 128, 0, stream>>>(C1, C2);
    if (l < 2) {
      k_out<true><<<dim3(NB, NC), 128, 0, stream>>>(
          h, C1, C2, e1s, e2s, perm, kcut, alpha, beta, gat_b + l * 128,
          bn_g + l * 128, bn_b + l * 128, bn_m + l * 128, bn_v + l * 128, x);
    } else {
      k_out<false><<<dim3(NB, NC), 128, 0, stream>>>(
          h, C1, C2, e1s, e2s, perm, kcut, alpha, beta, gat_b + 2 * 128,
          nullptr, nullptr, nullptr, nullptr, x);
    }
  }
}

// Round 8
// 330.967 us; speedup vs baseline: 1.1547x; 1.1547x over previous
//
#include <hip/hip_runtime.h>
#include <hip/hip_bf16.h>

#define BN_EPS 1e-5f
#define NB 64
#define NN 1000
#define NP 1024
#define HD 128
#define CS 8
#define NC 125  // NN/CS exactly

typedef short bf16x8 __attribute__((ext_vector_type(8)));
typedef float f32x4 __attribute__((ext_vector_type(4)));

__device__ __forceinline__ unsigned short f2b(float f) {
  __hip_bfloat16 h = __float2bfloat16(f);
  return *reinterpret_cast<unsigned short*>(&h);
}

// ---------------------------------------------------------------------------
// WT[l][n][k] = bf16(W[l][k][n]) for the 3 GAT layers. 49152 elements.
// ---------------------------------------------------------------------------
__global__ __launch_bounds__(256) void k_wprep(const float* __restrict__ W,
                                               unsigned short* __restrict__ WT) {
  int idx = blockIdx.x * 256 + threadIdx.x;  // < 49152
  int lay = idx >> 14;
  int rem = idx & 16383;
  int n = rem >> 7, k = rem & 127;
  WT[idx] = f2b(W[lay * 16384 + k * 128 + n]);
}

// ---------------------------------------------------------------------------
// Embedding MLP, register-tiled. 64 nodes/block. Writes xb (bf16).
// ---------------------------------------------------------------------------
__global__ __launch_bounds__(256) void k_embed(
    const float* __restrict__ locs,
    const float* __restrict__ W0, const float* __restrict__ b0,
    const float* __restrict__ W1, const float* __restrict__ b1,
    const float* __restrict__ g1, const float* __restrict__ be1,
    const float* __restrict__ m1, const float* __restrict__ v1,
    const float* __restrict__ Wo, const float* __restrict__ bo,
    unsigned short* __restrict__ xb) {
  __shared__ float z1T[64][68];
  __shared__ float z2T[64][68];
  int tid = threadIdx.x;
  long base = (long)blockIdx.x * 64;

  {
    int d = tid & 63;
    int q = tid >> 6;
    float w0x = W0[d], w0y = W0[64 + d], bb = b0[d];
#pragma unroll
    for (int g = 0; g < 4; ++g) {
      float vv[4];
#pragma unroll
      for (int i = 0; i < 4; ++i) {
        int n = g * 16 + q * 4 + i;
        float lx = locs[(base + n) * 2 + 0];
        float ly = locs[(base + n) * 2 + 1];
        vv[i] = fmaxf(fmaf(lx, w0x, fmaf(ly, w0y, bb)), 0.f);
      }
      *(float4*)&z1T[d][g * 16 + q * 4] = make_float4(vv[0], vv[1], vv[2], vv[3]);
    }
  }
  __syncthreads();

  int nt = tid & 15;
  int dt = tid >> 4;

  {
    float acc[4][4];
#pragma unroll
    for (int i = 0; i < 4; ++i)
#pragma unroll
      for (int j = 0; j < 4; ++j) acc[i][j] = 0.f;
#pragma unroll 4
    for (int k = 0; k < 64; ++k) {
      float4 zv = *(const float4*)&z1T[k][4 * nt];
      float4 wv = *(const float4*)&W1[k * 64 + 4 * dt];
      float zz[4] = {zv.x, zv.y, zv.z, zv.w};
      float ww[4] = {wv.x, wv.y, wv.z, wv.w};
#pragma unroll
      for (int i = 0; i < 4; ++i)
#pragma unroll
        for (int j = 0; j < 4; ++j) acc[i][j] = fmaf(zz[i], ww[j], acc[i][j]);
    }
    float4 b1v = *(const float4*)&b1[4 * dt];
    float4 g1v = *(const float4*)&g1[4 * dt];
    float4 bev = *(const float4*)&be1[4 * dt];
    float4 m1v = *(const float4*)&m1[4 * dt];
    float4 v1v = *(const float4*)&v1[4 * dt];
    float bbv[4] = {b1v.x, b1v.y, b1v.z, b1v.w};
    float ggv[4] = {g1v.x, g1v.y, g1v.z, g1v.w};
    float eev[4] = {bev.x, bev.y, bev.z, bev.w};
    float mmv[4] = {m1v.x, m1v.y, m1v.z, m1v.w};
    float vvv[4] = {v1v.x, v1v.y, v1v.z, v1v.w};
#pragma unroll
    for (int j = 0; j < 4; ++j) {
      float sc = ggv[j] * rsqrtf(vvv[j] + BN_EPS);
      float sh = eev[j] - mmv[j] * sc;
      float o[4];
#pragma unroll
      for (int i = 0; i < 4; ++i)
        o[i] = fmaxf(fmaf(acc[i][j] + bbv[j], sc, sh), 0.f);
      *(float4*)&z2T[4 * dt + j][4 * nt] = make_float4(o[0], o[1], o[2], o[3]);
    }
  }
  __syncthreads();

  {
    float acc[4][8];
#pragma unroll
    for (int i = 0; i < 4; ++i)
#pragma unroll
      for (int j = 0; j < 8; ++j) acc[i][j] = 0.f;
#pragma unroll 2
    for (int k = 0; k < 64; ++k) {
      float4 zv = *(const float4*)&z2T[k][4 * nt];
      float4 wa = *(const float4*)&Wo[k * 128 + 4 * dt];
      float4 wb = *(const float4*)&Wo[k * 128 + 64 + 4 * dt];
      float zz[4] = {zv.x, zv.y, zv.z, zv.w};
      float w0[4] = {wa.x, wa.y, wa.z, wa.w};
      float w1[4] = {wb.x, wb.y, wb.z, wb.w};
#pragma unroll
      for (int i = 0; i < 4; ++i) {
#pragma unroll
        for (int j = 0; j < 4; ++j) {
          acc[i][j] = fmaf(zz[i], w0[j], acc[i][j]);
          acc[i][4 + j] = fmaf(zz[i], w1[j], acc[i][4 + j]);
        }
      }
    }
    float4 bo0 = *(const float4*)&bo[4 * dt];
    float4 bo1 = *(const float4*)&bo[64 + 4 * dt];
    float bb0[4] = {bo0.x, bo0.y, bo0.z, bo0.w};
    float bb1[4] = {bo1.x, bo1.y, bo1.z, bo1.w};
#pragma unroll
    for (int i = 0; i < 4; ++i) {
      ushort4 p0, p1;
      p0.x = f2b(acc[i][0] + bb0[0]); p0.y = f2b(acc[i][1] + bb0[1]);
      p0.z = f2b(acc[i][2] + bb0[2]); p0.w = f2b(acc[i][3] + bb0[3]);
      p1.x = f2b(acc[i][4] + bb1[0]); p1.y = f2b(acc[i][5] + bb1[1]);
      p1.z = f2b(acc[i][6] + bb1[2]); p1.w = f2b(acc[i][7] + bb1[3]);
      *(ushort4*)&xb[(base + 4 * nt + i) * 128 + 4 * dt] = p0;
      *(ushort4*)&xb[(base + 4 * nt + i) * 128 + 64 + 4 * dt] = p1;
    }
  }
}

// ---------------------------------------------------------------------------
// h = xb @ W via MFMA 16x16x32 bf16. No LDS. Block = 4 waves, wave = 16 rows.
// A-frag: lane l -> row = l&15, k = ks*32 + (l>>4)*8 + j  (xb rows, b128)
// B-frag: lane l -> col = l&15, k = ks*32 + (l>>4)*8 + j  (WT rows, b128, L1)
// D: col = l&15, row = (l>>4)*4 + reg  [m89-verified]
// Epilogue: h f32 store + fused e_src/e_dst row dots (16-lane shuffle).
// ---------------------------------------------------------------------------
__global__ __launch_bounds__(256) void k_gemm_e(
    const unsigned short* __restrict__ xb, const unsigned short* __restrict__ WT,
    const float* __restrict__ asrc, const float* __restrict__ adst,
    float* __restrict__ h, float* __restrict__ es, float* __restrict__ ed) {
  int tid = threadIdx.x;
  int w = tid >> 6, l = tid & 63;
  long rowbase = (long)blockIdx.x * 64 + w * 16;
  int r = l & 15, g = l >> 4;

  f32x4 acc[8];
#pragma unroll
  for (int n = 0; n < 8; ++n) acc[n] = {0.f, 0.f, 0.f, 0.f};

#pragma unroll
  for (int ks = 0; ks < 4; ++ks) {
    bf16x8 a = *(const bf16x8*)&xb[(rowbase + r) * 128 + ks * 32 + g * 8];
#pragma unroll
    for (int n = 0; n < 8; ++n) {
      bf16x8 bfr = *(const bf16x8*)&WT[(n * 16 + r) * 128 + ks * 32 + g * 8];
      acc[n] = __builtin_amdgcn_mfma_f32_16x16x32_bf16(a, bfr, acc[n], 0, 0, 0);
    }
  }

  float ps[4] = {0.f, 0.f, 0.f, 0.f};
  float pd[4] = {0.f, 0.f, 0.f, 0.f};
#pragma unroll
  for (int n = 0; n < 8; ++n) {
    float sa = asrc[n * 16 + r];
    float sd = adst[n * 16 + r];
#pragma unroll
    for (int rr = 0; rr < 4; ++rr) {
      float v = acc[n][rr];
      h[(rowbase + g * 4 + rr) * 128 + n * 16 + r] = v;
      ps[rr] = fmaf(v, sa, ps[rr]);
      pd[rr] = fmaf(v, sd, pd[rr]);
    }
  }
#pragma unroll
  for (int rr = 0; rr < 4; ++rr) {
#pragma unroll
    for (int m = 1; m <= 8; m <<= 1) {
      ps[rr] += __shfl_xor(ps[rr], m, 64);
      pd[rr] += __shfl_xor(pd[rr], m, 64);
    }
  }
  if (r == 0) {
#pragma unroll
    for (int rr = 0; rr < 4; ++rr) {
      es[rowbase + g * 4 + rr] = ps[rr];
      ed[rowbase + g * 4 + rr] = pd[rr];
    }
  }
}

// ---------------------------------------------------------------------------
// Per batch: sort s (asc, with perm), e1/e2 prefix scan, per-target coeffs.
// ---------------------------------------------------------------------------
__global__ __launch_bounds__(256) void k_sort(
    const float* __restrict__ es, const float* __restrict__ ed,
    float* __restrict__ e1s, float* __restrict__ e2s, int* __restrict__ perm,
    int* __restrict__ kcut, float* __restrict__ alpha,
    float* __restrict__ beta) {
  __shared__ float ss[NP];
  __shared__ int id[NP];
  __shared__ float2 sa[NP];
  __shared__ float2 sb[NP];
  int tid = threadIdx.x, b = blockIdx.x;
  for (int i = tid; i < NP; i += 256) {
    ss[i] = (i < NN) ? es[b * NN + i] : INFINITY;
    id[i] = i;
  }
  for (int k = 2; k <= NP; k <<= 1) {
    for (int j = k >> 1; j > 0; j >>= 1) {
      __syncthreads();
      for (int i = tid; i < NP; i += 256) {
        int ixj = i ^ j;
        if (ixj > i) {
          bool up = ((i & k) == 0);
          float a = ss[i], c = ss[ixj];
          if ((a > c) == up) {
            ss[i] = c; ss[ixj] = a;
            int p = id[i]; id[i] = id[ixj]; id[ixj] = p;
          }
        }
      }
    }
  }
  __syncthreads();
  for (int i = tid; i < NP; i += 256) {
    float e1 = 0.f, e2 = 0.f;
    if (i < NN) {
      float s = ss[i];
      e1 = __expf(s);
      e2 = __expf(0.2f * s);
      e1s[b * NN + i] = e1;
      e2s[b * NN + i] = e2;
      perm[b * NN + i] = id[i];
    }
    sa[i] = make_float2(e1, e2);
  }
  __syncthreads();
  float2* src = sa;
  float2* dst = sb;
  for (int off = 1; off < NP; off <<= 1) {
    for (int i = tid; i < NP; i += 256) {
      float2 v = src[i];
      if (i >= off) {
        float2 u = src[i - off];
        v.x += u.x;
        v.y += u.y;
      }
      dst[i] = v;
    }
    __syncthreads();
    float2* t = src; src = dst; dst = t;
  }
  float s1tot = src[NN - 1].x;
  for (int i = tid; i < NN; i += 256) {
    float t = -ed[b * NN + i];
    int lo = 0, hi = NP;
    while (lo < hi) {
      int mid = (lo + hi) >> 1;
      if (ss[mid] <= t) lo = mid + 1; else hi = mid;
    }
    int k = lo;
    float p1 = (k > 0) ? src[k - 1].x : 0.f;
    float p2 = (k > 0) ? src[k - 1].y : 0.f;
    float Ed = __expf(-t);
    float Ed2 = __expf(-0.2f * t);
    float den = fmaf(Ed, s1tot - p1, Ed2 * p2);
    kcut[b * NN + i] = k;
    alpha[b * NN + i] = Ed / den;
    beta[b * NN + i] = Ed2 / den;
  }
}

// ---------------------------------------------------------------------------
// Per-chunk (8 sorted sources) weighted sums V1/V2 over dims.
// ---------------------------------------------------------------------------
__global__ __launch_bounds__(128) void k_chunk(
    const float* __restrict__ h, const float* __restrict__ e1s,
    const float* __restrict__ e2s, const int* __restrict__ perm,
    float* __restrict__ C1, float* __restrict__ C2) {
  int d = threadIdx.x, b = blockIdx.x, g = blockIdx.y;
  int c0 = g * 16, c1 = min(c0 + 16, NC);
  for (int c = c0; c < c1; ++c) {
    float v1 = 0.f, v2 = 0.f;
#pragma unroll
    for (int u = 0; u < CS; ++u) {
      int j = c * CS + u;
      int p = perm[b * NN + j];
      float hv = h[((long)b * NN + p) * HD + d];
      v1 = fmaf(e1s[b * NN + j], hv, v1);
      v2 = fmaf(e2s[b * NN + j], hv, v2);
    }
    C1[((long)b * (NC + 1) + c) * HD + d] = v1;
    C2[((long)b * (NC + 1) + c) * HD + d] = v2;
  }
}

// ---------------------------------------------------------------------------
// Exclusive prefix over chunks, LDS-staged. grid (NB, 2): 64 dims per block.
// Wave 0 scans C1, wave 1 scans C2 (serial in LDS, ~125 cheap iters).
// ---------------------------------------------------------------------------
__global__ __launch_bounds__(128) void k_cprefix(float* __restrict__ C1,
                                                 float* __restrict__ C2) {
  __shared__ float s1[NC + 1][64];
  __shared__ float s2[NC + 1][64];
  int tid = threadIdx.x, b = blockIdx.x, dh = blockIdx.y;
  long base = (long)b * (NC + 1) * HD + dh * 64;
  for (int i = tid; i < NC * 64; i += 128) {
    int c = i >> 6, d = i & 63;
    s1[c][d] = C1[base + (long)c * HD + d];
    s2[c][d] = C2[base + (long)c * HD + d];
  }
  __syncthreads();
  int d = tid & 63;
  if (tid < 64) {
    float r = 0.f;
    for (int c = 0; c < NC; ++c) {
      float v = s1[c][d];
      s1[c][d] = r;
      r += v;
    }
    s1[NC][d] = r;
  } else {
    float r = 0.f;
    for (int c = 0; c < NC; ++c) {
      float v = s2[c][d];
      s2[c][d] = r;
      r += v;
    }
    s2[NC][d] = r;
  }
  __syncthreads();
  for (int i = tid; i < (NC + 1) * 64; i += 128) {
    int c = i >> 6, d2 = i & 63;
    C1[base + (long)c * HD + d2] = s1[c][d2];
    C2[base + (long)c * HD + d2] = s2[c][d2];
  }
}

// ---------------------------------------------------------------------------
// out[i] = alpha_i*(T1 - C1[c_i] - partial1) + beta_i*(C2[c_i] + partial2)
// APPLY_BN=true: writes bf16 xb (intermediate); false: writes f32 out.
// ---------------------------------------------------------------------------
template <bool APPLY_BN>
__global__ __launch_bounds__(128) void k_out(
    const float* __restrict__ h, const float* __restrict__ C1,
    const float* __restrict__ C2, const float* __restrict__ e1s,
    const float* __restrict__ e2s, const int* __restrict__ perm,
    const int* __restrict__ kcut, const float* __restrict__ alpha,
    const float* __restrict__ beta, const float* __restrict__ bias,
    const float* __restrict__ bng, const float* __restrict__ bnb,
    const float* __restrict__ bnm, const float* __restrict__ bnv,
    float* __restrict__ xo, unsigned short* __restrict__ xbo) {
  int d = threadIdx.x, b = blockIdx.x;
  int i0 = blockIdx.y * 8;
  float T1 = C1[((long)b * (NC + 1) + NC) * HD + d];
  float bs = bias[d];
  float sc = 0.f, sh = 0.f;
  if (APPLY_BN) {
    float g = bng[d], bb = bnb[d], m = bnm[d], v = bnv[d];
    sc = g * rsqrtf(v + BN_EPS);
    sh = bb - m * sc;
  }
  for (int i = i0; i < i0 + 8; ++i) {
    int k = kcut[b * NN + i];
    float al = alpha[b * NN + i], bt = beta[b * NN + i];
    int c = k >> 3;
    float base1 = C1[((long)b * (NC + 1) + c) * HD + d];
    float base2 = C2[((long)b * (NC + 1) + c) * HD + d];
    float p1 = 0.f, p2 = 0.f;
    for (int j = c * CS; j < k; ++j) {
      int p = perm[b * NN + j];
      float hv = h[((long)b * NN + p) * HD + d];
      p1 = fmaf(e1s[b * NN + j], hv, p1);
      p2 = fmaf(e2s[b * NN + j], hv, p2);
    }
    float val = fmaf(al, T1 - base1 - p1, fmaf(bt, base2 + p2, bs));
    long off = ((long)b * NN + i) * HD + d;
    if (APPLY_BN) {
      xbo[off] = f2b(fmaxf(fmaf(val, sc, sh), 0.f));
    } else {
      xo[off] = val;
    }
  }
}

extern "C" void kernel_launch(void* const* d_in, const int* in_sizes, int n_in,
                              void* d_out, int out_size, void* d_ws,
                              size_t ws_size, hipStream_t stream) {
  const float* locs = (const float*)d_in[0];
  const float* le_W0 = (const float*)d_in[1];
  const float* le_b0 = (const float*)d_in[2];
  const float* le_W1 = (const float*)d_in[3];
  const float* le_b1 = (const float*)d_in[4];
  const float* le_bn_g = (const float*)d_in[5];
  const float* le_bn_b = (const float*)d_in[6];
  const float* le_bn_m = (const float*)d_in[7];
  const float* le_bn_v = (const float*)d_in[8];
  const float* le_Wo = (const float*)d_in[9];
  const float* le_bo = (const float*)d_in[10];
  const float* gat_W = (const float*)d_in[11];
  const float* gat_asrc = (const float*)d_in[12];
  const float* gat_adst = (const float*)d_in[13];
  const float* gat_b = (const float*)d_in[14];
  const float* bn_g = (const float*)d_in[15];
  const float* bn_b = (const float*)d_in[16];
  const float* bn_m = (const float*)d_in[17];
  const float* bn_v = (const float*)d_in[18];

  float* out = (float*)d_out;              // final f32 output
  float* h = (float*)d_ws;                 // 8,192,000 f32
  float* C1 = h + 8192000;                 // 1,032,192
  float* C2 = C1 + 1032192;                // 1,032,192
  float* es = C2 + 1032192;
  float* ed = es + 64000;
  float* e1s = ed + 64000;
  float* e2s = e1s + 64000;
  float* alpha = e2s + 64000;
  float* beta = alpha + 64000;
  int* perm = (int*)(beta + 64000);
  int* kcut = perm + 64000;
  unsigned short* xb = (unsigned short*)(kcut + 64000);  // 8,192,000 bf16
  unsigned short* WT = xb + 8192000;                      // 49,152 bf16

  k_wprep<<<192, 256, 0, stream>>>(gat_W, WT);
  k_embed<<<1000, 256, 0, stream>>>(locs, le_W0, le_b0, le_W1, le_b1, le_bn_g,
                                    le_bn_b, le_bn_m, le_bn_v, le_Wo, le_bo,
                                    xb);
  for (int l = 0; l < 3; ++l) {
    k_gemm_e<<<1000, 256, 0, stream>>>(xb, WT + l * 16384,
                                       gat_asrc + l * 128, gat_adst + l * 128,
                                       h, es, ed);
    k_sort<<<NB, 256, 0, stream>>>(es, ed, e1s, e2s, perm, kcut, alpha, beta);
    k_chunk<<<dim3(NB, 8), 128, 0, stream>>>(h, e1s, e2s, perm, C1, C2);
    k_cprefix<<<dim3(NB, 2), 128, 0, stream>>>(C1, C2);
    if (l < 2) {
      k_out<true><<<dim3(NB, NC), 128, 0, stream>>>(
          h, C1, C2, e1s, e2s, perm, kcut, alpha, beta, gat_b + l * 128,
          bn_g + l * 128, bn_b + l * 128, bn_m + l * 128, bn_v + l * 128,
          nullptr, xb);
    } else {
      k_out<false><<<dim3(NB, NC), 128, 0, stream>>>(
          h, C1, C2, e1s, e2s, perm, kcut, alpha, beta, gat_b + 2 * 128,
          nullptr, nullptr, nullptr, nullptr, out, nullptr);
    }
  }
}

// Round 10
// 298.145 us; speedup vs baseline: 1.2818x; 1.1101x over previous
//
#include <hip/hip_runtime.h>
#include <hip/hip_bf16.h>

#define BN_EPS 1e-5f
#define NB 64
#define NN 1000
#define NP 1024
#define HD 128
#define CS 8
#define NC 125  // NN/CS exactly

typedef short bf16x8 __attribute__((ext_vector_type(8)));
typedef float f32x4 __attribute__((ext_vector_type(4)));

__device__ __forceinline__ unsigned short f2b(float f) {
  __hip_bfloat16 h = __float2bfloat16(f);
  return *reinterpret_cast<unsigned short*>(&h);
}
__device__ __forceinline__ float b2f(unsigned short u) {
  unsigned v = ((unsigned)u) << 16;
  return __uint_as_float(v);
}
// monotonic float -> uint (unsigned compare == float compare)
__device__ __forceinline__ unsigned tkey(float f) {
  unsigned u = __float_as_uint(f);
  return u ^ ((unsigned)((int)u >> 31) | 0x80000000u);
}

// ---------------------------------------------------------------------------
// Embedding MLP, register-tiled. 64 nodes/block. Writes xb (bf16).
// Blocks 0..191 also transpose the 3 GAT weights into WT (bf16).
// ---------------------------------------------------------------------------
__global__ __launch_bounds__(256) void k_embed(
    const float* __restrict__ locs,
    const float* __restrict__ W0, const float* __restrict__ b0,
    const float* __restrict__ W1, const float* __restrict__ b1,
    const float* __restrict__ g1, const float* __restrict__ be1,
    const float* __restrict__ m1, const float* __restrict__ v1,
    const float* __restrict__ Wo, const float* __restrict__ bo,
    const float* __restrict__ gatW, unsigned short* __restrict__ WT,
    unsigned short* __restrict__ xb) {
  __shared__ float z1T[64][68];
  __shared__ float z2T[64][68];
  int tid = threadIdx.x;
  long base = (long)blockIdx.x * 64;

  if (blockIdx.x < 192) {  // fused W transpose: 49152 elems
    int idx = blockIdx.x * 256 + tid;
    int lay = idx >> 14, rem = idx & 16383;
    int n = rem >> 7, kk = rem & 127;
    WT[idx] = f2b(gatW[lay * 16384 + kk * 128 + n]);
  }

  {
    int d = tid & 63;
    int q = tid >> 6;
    float w0x = W0[d], w0y = W0[64 + d], bb = b0[d];
#pragma unroll
    for (int g = 0; g < 4; ++g) {
      float vv[4];
#pragma unroll
      for (int i = 0; i < 4; ++i) {
        int n = g * 16 + q * 4 + i;
        float lx = locs[(base + n) * 2 + 0];
        float ly = locs[(base + n) * 2 + 1];
        vv[i] = fmaxf(fmaf(lx, w0x, fmaf(ly, w0y, bb)), 0.f);
      }
      *(float4*)&z1T[d][g * 16 + q * 4] = make_float4(vv[0], vv[1], vv[2], vv[3]);
    }
  }
  __syncthreads();

  int nt = tid & 15;
  int dt = tid >> 4;

  {
    float acc[4][4];
#pragma unroll
    for (int i = 0; i < 4; ++i)
#pragma unroll
      for (int j = 0; j < 4; ++j) acc[i][j] = 0.f;
#pragma unroll 4
    for (int k = 0; k < 64; ++k) {
      float4 zv = *(const float4*)&z1T[k][4 * nt];
      float4 wv = *(const float4*)&W1[k * 64 + 4 * dt];
      float zz[4] = {zv.x, zv.y, zv.z, zv.w};
      float ww[4] = {wv.x, wv.y, wv.z, wv.w};
#pragma unroll
      for (int i = 0; i < 4; ++i)
#pragma unroll
        for (int j = 0; j < 4; ++j) acc[i][j] = fmaf(zz[i], ww[j], acc[i][j]);
    }
    float4 b1v = *(const float4*)&b1[4 * dt];
    float4 g1v = *(const float4*)&g1[4 * dt];
    float4 bev = *(const float4*)&be1[4 * dt];
    float4 m1v = *(const float4*)&m1[4 * dt];
    float4 v1v = *(const float4*)&v1[4 * dt];
    float bbv[4] = {b1v.x, b1v.y, b1v.z, b1v.w};
    float ggv[4] = {g1v.x, g1v.y, g1v.z, g1v.w};
    float eev[4] = {bev.x, bev.y, bev.z, bev.w};
    float mmv[4] = {m1v.x, m1v.y, m1v.z, m1v.w};
    float vvv[4] = {v1v.x, v1v.y, v1v.z, v1v.w};
#pragma unroll
    for (int j = 0; j < 4; ++j) {
      float sc = ggv[j] * rsqrtf(vvv[j] + BN_EPS);
      float sh = eev[j] - mmv[j] * sc;
      float o[4];
#pragma unroll
      for (int i = 0; i < 4; ++i)
        o[i] = fmaxf(fmaf(acc[i][j] + bbv[j], sc, sh), 0.f);
      *(float4*)&z2T[4 * dt + j][4 * nt] = make_float4(o[0], o[1], o[2], o[3]);
    }
  }
  __syncthreads();

  {
    float acc[4][8];
#pragma unroll
    for (int i = 0; i < 4; ++i)
#pragma unroll
      for (int j = 0; j < 8; ++j) acc[i][j] = 0.f;
#pragma unroll 2
    for (int k = 0; k < 64; ++k) {
      float4 zv = *(const float4*)&z2T[k][4 * nt];
      float4 wa = *(const float4*)&Wo[k * 128 + 4 * dt];
      float4 wb = *(const float4*)&Wo[k * 128 + 64 + 4 * dt];
      float zz[4] = {zv.x, zv.y, zv.z, zv.w};
      float w0[4] = {wa.x, wa.y, wa.z, wa.w};
      float w1[4] = {wb.x, wb.y, wb.z, wb.w};
#pragma unroll
      for (int i = 0; i < 4; ++i) {
#pragma unroll
        for (int j = 0; j < 4; ++j) {
          acc[i][j] = fmaf(zz[i], w0[j], acc[i][j]);
          acc[i][4 + j] = fmaf(zz[i], w1[j], acc[i][4 + j]);
        }
      }
    }
    float4 bo0 = *(const float4*)&bo[4 * dt];
    float4 bo1 = *(const float4*)&bo[64 + 4 * dt];
    float bb0[4] = {bo0.x, bo0.y, bo0.z, bo0.w};
    float bb1[4] = {bo1.x, bo1.y, bo1.z, bo1.w};
#pragma unroll
    for (int i = 0; i < 4; ++i) {
      ushort4 p0, p1;
      p0.x = f2b(acc[i][0] + bb0[0]); p0.y = f2b(acc[i][1] + bb0[1]);
      p0.z = f2b(acc[i][2] + bb0[2]); p0.w = f2b(acc[i][3] + bb0[3]);
      p1.x = f2b(acc[i][4] + bb1[0]); p1.y = f2b(acc[i][5] + bb1[1]);
      p1.z = f2b(acc[i][6] + bb1[2]); p1.w = f2b(acc[i][7] + bb1[3]);
      *(ushort4*)&xb[(base + 4 * nt + i) * 128 + 4 * dt] = p0;
      *(ushort4*)&xb[(base + 4 * nt + i) * 128 + 64 + 4 * dt] = p1;
    }
  }
}

// ---------------------------------------------------------------------------
// h = xb @ W via MFMA 16x16x32 bf16. No LDS. Block = 4 waves, wave = 16 rows.
// Writes hb (bf16); e_src/e_dst dots from f32 accumulators.
// ---------------------------------------------------------------------------
__global__ __launch_bounds__(256) void k_gemm_e(
    const unsigned short* __restrict__ xb, const unsigned short* __restrict__ WT,
    const float* __restrict__ asrc, const float* __restrict__ adst,
    unsigned short* __restrict__ hb, float* __restrict__ es,
    float* __restrict__ ed) {
  int tid = threadIdx.x;
  int w = tid >> 6, l = tid & 63;
  long rowbase = (long)blockIdx.x * 64 + w * 16;
  int r = l & 15, g = l >> 4;

  f32x4 acc[8];
#pragma unroll
  for (int n = 0; n < 8; ++n) acc[n] = {0.f, 0.f, 0.f, 0.f};

#pragma unroll
  for (int ks = 0; ks < 4; ++ks) {
    bf16x8 a = *(const bf16x8*)&xb[(rowbase + r) * 128 + ks * 32 + g * 8];
#pragma unroll
    for (int n = 0; n < 8; ++n) {
      bf16x8 bfr = *(const bf16x8*)&WT[(n * 16 + r) * 128 + ks * 32 + g * 8];
      acc[n] = __builtin_amdgcn_mfma_f32_16x16x32_bf16(a, bfr, acc[n], 0, 0, 0);
    }
  }

  float ps[4] = {0.f, 0.f, 0.f, 0.f};
  float pd[4] = {0.f, 0.f, 0.f, 0.f};
#pragma unroll
  for (int n = 0; n < 8; ++n) {
    float sa = asrc[n * 16 + r];
    float sd = adst[n * 16 + r];
#pragma unroll
    for (int rr = 0; rr < 4; ++rr) {
      float v = acc[n][rr];
      hb[(rowbase + g * 4 + rr) * 128 + n * 16 + r] = f2b(v);
      ps[rr] = fmaf(v, sa, ps[rr]);
      pd[rr] = fmaf(v, sd, pd[rr]);
    }
  }
#pragma unroll
  for (int rr = 0; rr < 4; ++rr) {
#pragma unroll
    for (int m = 1; m <= 8; m <<= 1) {
      ps[rr] += __shfl_xor(ps[rr], m, 64);
      pd[rr] += __shfl_xor(pd[rr], m, 64);
    }
  }
  if (r == 0) {
#pragma unroll
    for (int rr = 0; rr < 4; ++rr) {
      es[rowbase + g * 4 + rr] = ps[rr];
      ed[rowbase + g * 4 + rr] = pd[rr];
    }
  }
}

#define CEX(a, b, up)                         \
  do {                                        \
    if (((a) > (b)) == (up)) {                \
      unsigned long long _t = (a);            \
      (a) = (b);                              \
      (b) = _t;                               \
    }                                         \
  } while (0)

// ---------------------------------------------------------------------------
// Per batch: u64-packed bitonic sort (key=transformed s | idx), e1/e2 scan,
// per-target binsearch coeffs. 64 blocks x 256 threads.
// ---------------------------------------------------------------------------
__global__ __launch_bounds__(256) void k_sort(
    const float* __restrict__ es, const float* __restrict__ ed,
    float* __restrict__ e1s, float* __restrict__ e2s, int* __restrict__ perm,
    int* __restrict__ kcut, float* __restrict__ alpha,
    float* __restrict__ beta) {
  __shared__ unsigned long long keys[NP];
  __shared__ float2 sa[NP];
  __shared__ float2 sb[NP];
  int tid = threadIdx.x, b = blockIdx.x;
  for (int i = tid; i < NP; i += 256) {
    unsigned long long kk;
    if (i < NN) {
      kk = ((unsigned long long)tkey(es[b * NN + i]) << 32) | (unsigned)i;
    } else {
      kk = (0xFF800000ull << 32) | (unsigned)i;  // +INF pad
    }
    keys[i] = kk;
  }
  __syncthreads();
  int base = tid * 4;
  // k=2 and k=4 phases: fully thread-local
  {
    unsigned long long q0 = keys[base], q1 = keys[base + 1];
    unsigned long long q2 = keys[base + 2], q3 = keys[base + 3];
    CEX(q0, q1, true);
    CEX(q2, q3, false);
    bool up4 = ((base & 4) == 0);
    CEX(q0, q2, up4); CEX(q1, q3, up4); CEX(q0, q1, up4); CEX(q2, q3, up4);
    keys[base] = q0; keys[base + 1] = q1; keys[base + 2] = q2; keys[base + 3] = q3;
  }
  __syncthreads();
  for (int k = 8; k <= NP; k <<= 1) {
    for (int j = k >> 1; j >= 4; j >>= 1) {
      for (int i = tid; i < NP; i += 256) {
        int ixj = i ^ j;
        if (ixj > i) {
          bool up = ((i & k) == 0);
          unsigned long long a = keys[i], c = keys[ixj];
          if ((a > c) == up) { keys[i] = c; keys[ixj] = a; }
        }
      }
      __syncthreads();
    }
    {
      bool up = ((base & k) == 0);
      unsigned long long q0 = keys[base], q1 = keys[base + 1];
      unsigned long long q2 = keys[base + 2], q3 = keys[base + 3];
      CEX(q0, q2, up); CEX(q1, q3, up); CEX(q0, q1, up); CEX(q2, q3, up);
      keys[base] = q0; keys[base + 1] = q1; keys[base + 2] = q2; keys[base + 3] = q3;
    }
    __syncthreads();
  }
  // extract sorted s -> e1/e2/perm; seed scan
  for (int i = tid; i < NP; i += 256) {
    float e1 = 0.f, e2 = 0.f;
    if (i < NN) {
      unsigned long long kk = keys[i];
      unsigned m = (unsigned)(kk >> 32);
      unsigned u = (m & 0x80000000u) ? (m ^ 0x80000000u) : ~m;
      float s = __uint_as_float(u);
      e1 = __expf(s);
      e2 = __expf(0.2f * s);
      e1s[b * NN + i] = e1;
      e2s[b * NN + i] = e2;
      perm[b * NN + i] = (int)(unsigned)kk;
    }
    sa[i] = make_float2(e1, e2);
  }
  __syncthreads();
  float2* src = sa;
  float2* dst = sb;
  for (int off = 1; off < NP; off <<= 1) {
    for (int i = tid; i < NP; i += 256) {
      float2 v = src[i];
      if (i >= off) {
        float2 u = src[i - off];
        v.x += u.x;
        v.y += u.y;
      }
      dst[i] = v;
    }
    __syncthreads();
    float2* t = src; src = dst; dst = t;
  }
  float s1tot = src[NN - 1].x;
  for (int i = tid; i < NN; i += 256) {
    float di = ed[b * NN + i];
    unsigned tt = tkey(-di);
    int lo = 0, hi = NP;
    while (lo < hi) {
      int mid = (lo + hi) >> 1;
      if ((unsigned)(keys[mid] >> 32) <= tt) lo = mid + 1; else hi = mid;
    }
    int k = lo;  // #{s_j <= t_i}, <= NN (pads are +INF)
    float p1 = (k > 0) ? src[k - 1].x : 0.f;
    float p2 = (k > 0) ? src[k - 1].y : 0.f;
    float Ed = __expf(di);
    float Ed2 = __expf(0.2f * di);
    float den = fmaf(Ed, s1tot - p1, Ed2 * p2);
    kcut[b * NN + i] = k;
    alpha[b * NN + i] = Ed / den;
    beta[b * NN + i] = Ed2 / den;
  }
}

// ---------------------------------------------------------------------------
// Per-chunk (8 sorted sources) weighted sums V1/V2 over dims (h in bf16).
// ---------------------------------------------------------------------------
__global__ __launch_bounds__(128) void k_chunk(
    const unsigned short* __restrict__ hb, const float* __restrict__ e1s,
    const float* __restrict__ e2s, const int* __restrict__ perm,
    float* __restrict__ C1, float* __restrict__ C2) {
  int d = threadIdx.x, b = blockIdx.x, g = blockIdx.y;
  int c0 = g * 16, c1 = min(c0 + 16, NC);
  for (int c = c0; c < c1; ++c) {
    float v1 = 0.f, v2 = 0.f;
#pragma unroll
    for (int u = 0; u < CS; ++u) {
      int j = c * CS + u;
      int p = perm[b * NN + j];
      float hv = b2f(hb[((long)b * NN + p) * HD + d]);
      v1 = fmaf(e1s[b * NN + j], hv, v1);
      v2 = fmaf(e2s[b * NN + j], hv, v2);
    }
    C1[((long)b * (NC + 1) + c) * HD + d] = v1;
    C2[((long)b * (NC + 1) + c) * HD + d] = v2;
  }
}

// ---------------------------------------------------------------------------
// Exclusive prefix over chunks, LDS-staged. grid (NB, 2): 64 dims per block.
// ---------------------------------------------------------------------------
__global__ __launch_bounds__(128) void k_cprefix(float* __restrict__ C1,
                                                 float* __restrict__ C2) {
  __shared__ float s1[NC + 1][64];
  __shared__ float s2[NC + 1][64];
  int tid = threadIdx.x, b = blockIdx.x, dh = blockIdx.y;
  long base = (long)b * (NC + 1) * HD + dh * 64;
  for (int i = tid; i < NC * 64; i += 128) {
    int c = i >> 6, d = i & 63;
    s1[c][d] = C1[base + (long)c * HD + d];
    s2[c][d] = C2[base + (long)c * HD + d];
  }
  __syncthreads();
  int d = tid & 63;
  if (tid < 64) {
    float r = 0.f;
    for (int c = 0; c < NC; ++c) {
      float v = s1[c][d];
      s1[c][d] = r;
      r += v;
    }
    s1[NC][d] = r;
  } else {
    float r = 0.f;
    for (int c = 0; c < NC; ++c) {
      float v = s2[c][d];
      s2[c][d] = r;
      r += v;
    }
    s2[NC][d] = r;
  }
  __syncthreads();
  for (int i = tid; i < (NC + 1) * 64; i += 128) {
    int c = i >> 6, d2 = i & 63;
    C1[base + (long)c * HD + d2] = s1[c][d2];
    C2[base + (long)c * HD + d2] = s2[c][d2];
  }
}

// ---------------------------------------------------------------------------
// out[i] = alpha_i*(T1 - C1[c_i] - partial1) + beta_i*(C2[c_i] + partial2)
// APPLY_BN=true: writes bf16 xb (intermediate); false: writes f32 out.
// ---------------------------------------------------------------------------
template <bool APPLY_BN>
__global__ __launch_bounds__(128) void k_out(
    const unsigned short* __restrict__ hb, const float* __restrict__ C1,
    const float* __restrict__ C2, const float* __restrict__ e1s,
    const float* __restrict__ e2s, const int* __restrict__ perm,
    const int* __restrict__ kcut, const float* __restrict__ alpha,
    const float* __restrict__ beta, const float* __restrict__ bias,
    const float* __restrict__ bng, const float* __restrict__ bnb,
    const float* __restrict__ bnm, const float* __restrict__ bnv,
    float* __restrict__ xo, unsigned short* __restrict__ xbo) {
  int d = threadIdx.x, b = blockIdx.x;
  int i0 = blockIdx.y * 8;
  float T1 = C1[((long)b * (NC + 1) + NC) * HD + d];
  float bs = bias[d];
  float sc = 0.f, sh = 0.f;
  if (APPLY_BN) {
    float g = bng[d], bb = bnb[d], m = bnm[d], v = bnv[d];
    sc = g * rsqrtf(v + BN_EPS);
    sh = bb - m * sc;
  }
  for (int i = i0; i < i0 + 8; ++i) {
    int k = kcut[b * NN + i];
    float al = alpha[b * NN + i], bt = beta[b * NN + i];
    int c = k >> 3;
    float base1 = C1[((long)b * (NC + 1) + c) * HD + d];
    float base2 = C2[((long)b * (NC + 1) + c) * HD + d];
    float p1 = 0.f, p2 = 0.f;
    for (int j = c * CS; j < k; ++j) {
      int p = perm[b * NN + j];
      float hv = b2f(hb[((long)b * NN + p) * HD + d]);
      p1 = fmaf(e1s[b * NN + j], hv, p1);
      p2 = fmaf(e2s[b * NN + j], hv, p2);
    }
    float val = fmaf(al, T1 - base1 - p1, fmaf(bt, base2 + p2, bs));
    long off = ((long)b * NN + i) * HD + d;
    if (APPLY_BN) {
      xbo[off] = f2b(fmaxf(fmaf(val, sc, sh), 0.f));
    } else {
      xo[off] = val;
    }
  }
}

extern "C" void kernel_launch(void* const* d_in, const int* in_sizes, int n_in,
                              void* d_out, int out_size, void* d_ws,
                              size_t ws_size, hipStream_t stream) {
  const float* locs = (const float*)d_in[0];
  const float* le_W0 = (const float*)d_in[1];
  const float* le_b0 = (const float*)d_in[2];
  const float* le_W1 = (const float*)d_in[3];
  const float* le_b1 = (const float*)d_in[4];
  const float* le_bn_g = (const float*)d_in[5];
  const float* le_bn_b = (const float*)d_in[6];
  const float* le_bn_m = (const float*)d_in[7];
  const float* le_bn_v = (const float*)d_in[8];
  const float* le_Wo = (const float*)d_in[9];
  const float* le_bo = (const float*)d_in[10];
  const float* gat_W = (const float*)d_in[11];
  const float* gat_asrc = (const float*)d_in[12];
  const float* gat_adst = (const float*)d_in[13];
  const float* gat_b = (const float*)d_in[14];
  const float* bn_g = (const float*)d_in[15];
  const float* bn_b = (const float*)d_in[16];
  const float* bn_m = (const float*)d_in[17];
  const float* bn_v = (const float*)d_in[18];

  float* out = (float*)d_out;                          // final f32 output
  unsigned short* hb = (unsigned short*)d_ws;          // 8,192,000 bf16
  float* C1 = (float*)(hb + 8192000);                  // 1,032,192 f32
  float* C2 = C1 + 1032192;                            // 1,032,192
  float* es = C2 + 1032192;
  float* ed = es + 64000;
  float* e1s = ed + 64000;
  float* e2s = e1s + 64000;
  float* alpha = e2s + 64000;
  float* beta = alpha + 64000;
  int* perm = (int*)(beta + 64000);
  int* kcut = perm + 64000;
  unsigned short* xb = (unsigned short*)(kcut + 64000);  // 8,192,000 bf16
  unsigned short* WT = xb + 8192000;                      // 49,152 bf16

  k_embed<<<1000, 256, 0, stream>>>(locs, le_W0, le_b0, le_W1, le_b1, le_bn_g,
                                    le_bn_b, le_bn_m, le_bn_v, le_Wo, le_bo,
                                    gat_W, WT, xb);
  for (int l = 0; l < 3; ++l) {
    k_gemm_e<<<1000, 256, 0, stream>>>(xb, WT + l * 16384,
                                       gat_asrc + l * 128, gat_adst + l * 128,
                                       hb, es, ed);
    k_sort<<<NB, 256, 0, stream>>>(es, ed, e1s, e2s, perm, kcut, alpha, beta);
    k_chunk<<<dim3(NB, 8), 128, 0, stream>>>(hb, e1s, e2s, perm, C1, C2);
    k_cprefix<<<dim3(NB, 2), 128, 0, stream>>>(C1, C2);
    if (l < 2) {
      k_out<true><<<dim3(NB, NC), 128, 0, stream>>>(
          hb, C1, C2, e1s, e2s, perm, kcut, alpha, beta, gat_b + l * 128,
          bn_g + l * 128, bn_b + l * 128, bn_m + l * 128, bn_v + l * 128,
          nullptr, xb);
    } else {
      k_out<false><<<dim3(NB, NC), 128, 0, stream>>>(
          hb, C1, C2, e1s, e2s, perm, kcut, alpha, beta, gat_b + 2 * 128,
          nullptr, nullptr, nullptr, nullptr, out, nullptr);
    }
  }
}

// Round 11
// 255.464 us; speedup vs baseline: 1.4960x; 1.1671x over previous
//
#include <hip/hip_runtime.h>
#include <hip/hip_bf16.h>

#define BN_EPS 1e-5f
#define NB 64
#define NN 1000
#define NP 1024
#define HD 128
#define CS 8
#define NC 125  // NN/CS exactly

typedef short bf16x8 __attribute__((ext_vector_type(8)));
typedef float f32x4 __attribute__((ext_vector_type(4)));

__device__ __forceinline__ unsigned short f2b(float f) {
  __hip_bfloat16 h = __float2bfloat16(f);
  return *reinterpret_cast<unsigned short*>(&h);
}
__device__ __forceinline__ float b2f(unsigned short u) {
  unsigned v = ((unsigned)u) << 16;
  return __uint_as_float(v);
}
// monotonic float -> uint (unsigned compare == float compare)
__device__ __forceinline__ unsigned tkey(float f) {
  unsigned u = __float_as_uint(f);
  return u ^ ((unsigned)((int)u >> 31) | 0x80000000u);
}

// ---------------------------------------------------------------------------
// Embedding MLP, register-tiled. 64 nodes/block. Writes xb (bf16).
// Blocks 0..191 also transpose the 3 GAT weights into WT (bf16).
// ---------------------------------------------------------------------------
__global__ __launch_bounds__(256) void k_embed(
    const float* __restrict__ locs,
    const float* __restrict__ W0, const float* __restrict__ b0,
    const float* __restrict__ W1, const float* __restrict__ b1,
    const float* __restrict__ g1, const float* __restrict__ be1,
    const float* __restrict__ m1, const float* __restrict__ v1,
    const float* __restrict__ Wo, const float* __restrict__ bo,
    const float* __restrict__ gatW, unsigned short* __restrict__ WT,
    unsigned short* __restrict__ xb) {
  __shared__ float z1T[64][68];
  __shared__ float z2T[64][68];
  int tid = threadIdx.x;
  long base = (long)blockIdx.x * 64;

  if (blockIdx.x < 192) {  // fused W transpose: 49152 elems
    int idx = blockIdx.x * 256 + tid;
    int lay = idx >> 14, rem = idx & 16383;
    int n = rem >> 7, kk = rem & 127;
    WT[idx] = f2b(gatW[lay * 16384 + kk * 128 + n]);
  }

  {
    int d = tid & 63;
    int q = tid >> 6;
    float w0x = W0[d], w0y = W0[64 + d], bb = b0[d];
#pragma unroll
    for (int g = 0; g < 4; ++g) {
      float vv[4];
#pragma unroll
      for (int i = 0; i < 4; ++i) {
        int n = g * 16 + q * 4 + i;
        float lx = locs[(base + n) * 2 + 0];
        float ly = locs[(base + n) * 2 + 1];
        vv[i] = fmaxf(fmaf(lx, w0x, fmaf(ly, w0y, bb)), 0.f);
      }
      *(float4*)&z1T[d][g * 16 + q * 4] = make_float4(vv[0], vv[1], vv[2], vv[3]);
    }
  }
  __syncthreads();

  int nt = tid & 15;
  int dt = tid >> 4;

  {
    float acc[4][4];
#pragma unroll
    for (int i = 0; i < 4; ++i)
#pragma unroll
      for (int j = 0; j < 4; ++j) acc[i][j] = 0.f;
#pragma unroll 4
    for (int k = 0; k < 64; ++k) {
      float4 zv = *(const float4*)&z1T[k][4 * nt];
      float4 wv = *(const float4*)&W1[k * 64 + 4 * dt];
      float zz[4] = {zv.x, zv.y, zv.z, zv.w};
      float ww[4] = {wv.x, wv.y, wv.z, wv.w};
#pragma unroll
      for (int i = 0; i < 4; ++i)
#pragma unroll
        for (int j = 0; j < 4; ++j) acc[i][j] = fmaf(zz[i], ww[j], acc[i][j]);
    }
    float4 b1v = *(const float4*)&b1[4 * dt];
    float4 g1v = *(const float4*)&g1[4 * dt];
    float4 bev = *(const float4*)&be1[4 * dt];
    float4 m1v = *(const float4*)&m1[4 * dt];
    float4 v1v = *(const float4*)&v1[4 * dt];
    float bbv[4] = {b1v.x, b1v.y, b1v.z, b1v.w};
    float ggv[4] = {g1v.x, g1v.y, g1v.z, g1v.w};
    float eev[4] = {bev.x, bev.y, bev.z, bev.w};
    float mmv[4] = {m1v.x, m1v.y, m1v.z, m1v.w};
    float vvv[4] = {v1v.x, v1v.y, v1v.z, v1v.w};
#pragma unroll
    for (int j = 0; j < 4; ++j) {
      float sc = ggv[j] * rsqrtf(vvv[j] + BN_EPS);
      float sh = eev[j] - mmv[j] * sc;
      float o[4];
#pragma unroll
      for (int i = 0; i < 4; ++i)
        o[i] = fmaxf(fmaf(acc[i][j] + bbv[j], sc, sh), 0.f);
      *(float4*)&z2T[4 * dt + j][4 * nt] = make_float4(o[0], o[1], o[2], o[3]);
    }
  }
  __syncthreads();

  {
    float acc[4][8];
#pragma unroll
    for (int i = 0; i < 4; ++i)
#pragma unroll
      for (int j = 0; j < 8; ++j) acc[i][j] = 0.f;
#pragma unroll 2
    for (int k = 0; k < 64; ++k) {
      float4 zv = *(const float4*)&z2T[k][4 * nt];
      float4 wa = *(const float4*)&Wo[k * 128 + 4 * dt];
      float4 wb = *(const float4*)&Wo[k * 128 + 64 + 4 * dt];
      float zz[4] = {zv.x, zv.y, zv.z, zv.w};
      float w0[4] = {wa.x, wa.y, wa.z, wa.w};
      float w1[4] = {wb.x, wb.y, wb.z, wb.w};
#pragma unroll
      for (int i = 0; i < 4; ++i) {
#pragma unroll
        for (int j = 0; j < 4; ++j) {
          acc[i][j] = fmaf(zz[i], w0[j], acc[i][j]);
          acc[i][4 + j] = fmaf(zz[i], w1[j], acc[i][4 + j]);
        }
      }
    }
    float4 bo0 = *(const float4*)&bo[4 * dt];
    float4 bo1 = *(const float4*)&bo[64 + 4 * dt];
    float bb0[4] = {bo0.x, bo0.y, bo0.z, bo0.w};
    float bb1[4] = {bo1.x, bo1.y, bo1.z, bo1.w};
#pragma unroll
    for (int i = 0; i < 4; ++i) {
      ushort4 p0, p1;
      p0.x = f2b(acc[i][0] + bb0[0]); p0.y = f2b(acc[i][1] + bb0[1]);
      p0.z = f2b(acc[i][2] + bb0[2]); p0.w = f2b(acc[i][3] + bb0[3]);
      p1.x = f2b(acc[i][4] + bb1[0]); p1.y = f2b(acc[i][5] + bb1[1]);
      p1.z = f2b(acc[i][6] + bb1[2]); p1.w = f2b(acc[i][7] + bb1[3]);
      *(ushort4*)&xb[(base + 4 * nt + i) * 128 + 4 * dt] = p0;
      *(ushort4*)&xb[(base + 4 * nt + i) * 128 + 64 + 4 * dt] = p1;
    }
  }
}

// ---------------------------------------------------------------------------
// h = xb @ W via MFMA 16x16x32 bf16. No LDS. Block = 4 waves, wave = 16 rows.
// Writes hb (bf16; wave stores are complete 32-B sectors); e dots from f32 acc.
// ---------------------------------------------------------------------------
__global__ __launch_bounds__(256) void k_gemm_e(
    const unsigned short* __restrict__ xb, const unsigned short* __restrict__ WT,
    const float* __restrict__ asrc, const float* __restrict__ adst,
    unsigned short* __restrict__ hb, float* __restrict__ es,
    float* __restrict__ ed) {
  int tid = threadIdx.x;
  int w = tid >> 6, l = tid & 63;
  long rowbase = (long)blockIdx.x * 64 + w * 16;
  int r = l & 15, g = l >> 4;

  f32x4 acc[8];
#pragma unroll
  for (int n = 0; n < 8; ++n) acc[n] = {0.f, 0.f, 0.f, 0.f};

#pragma unroll
  for (int ks = 0; ks < 4; ++ks) {
    bf16x8 a = *(const bf16x8*)&xb[(rowbase + r) * 128 + ks * 32 + g * 8];
#pragma unroll
    for (int n = 0; n < 8; ++n) {
      bf16x8 bfr = *(const bf16x8*)&WT[(n * 16 + r) * 128 + ks * 32 + g * 8];
      acc[n] = __builtin_amdgcn_mfma_f32_16x16x32_bf16(a, bfr, acc[n], 0, 0, 0);
    }
  }

  float ps[4] = {0.f, 0.f, 0.f, 0.f};
  float pd[4] = {0.f, 0.f, 0.f, 0.f};
#pragma unroll
  for (int n = 0; n < 8; ++n) {
    float sa = asrc[n * 16 + r];
    float sd = adst[n * 16 + r];
#pragma unroll
    for (int rr = 0; rr < 4; ++rr) {
      float v = acc[n][rr];
      hb[(rowbase + g * 4 + rr) * 128 + n * 16 + r] = f2b(v);
      ps[rr] = fmaf(v, sa, ps[rr]);
      pd[rr] = fmaf(v, sd, pd[rr]);
    }
  }
#pragma unroll
  for (int rr = 0; rr < 4; ++rr) {
#pragma unroll
    for (int m = 1; m <= 8; m <<= 1) {
      ps[rr] += __shfl_xor(ps[rr], m, 64);
      pd[rr] += __shfl_xor(pd[rr], m, 64);
    }
  }
  if (r == 0) {
#pragma unroll
    for (int rr = 0; rr < 4; ++rr) {
      es[rowbase + g * 4 + rr] = ps[rr];
      ed[rowbase + g * 4 + rr] = pd[rr];
    }
  }
}

#define CEX(a, b, up)                         \
  do {                                        \
    if (((a) > (b)) == (up)) {                \
      unsigned long long _t = (a);            \
      (a) = (b);                              \
      (b) = _t;                               \
    }                                         \
  } while (0)

// ---------------------------------------------------------------------------
// Per batch, 512 threads: u64-packed bitonic sort (2 elems/thread; j=1 pass in
// registers, LDS passes are single-iteration), hierarchical shfl scan of
// (e1,e2), per-target binsearch coefficients.
// ---------------------------------------------------------------------------
__global__ __launch_bounds__(512) void k_sort(
    const float* __restrict__ es, const float* __restrict__ ed,
    float* __restrict__ e1s, float* __restrict__ e2s, int* __restrict__ perm,
    int* __restrict__ kcut, float* __restrict__ alpha,
    float* __restrict__ beta) {
  __shared__ unsigned long long keys[NP];
  __shared__ float2 sc[NP];
  __shared__ float2 wtot[8];
  int tid = threadIdx.x, b = blockIdx.x;
  for (int i = tid; i < NP; i += 512) {
    unsigned long long kk;
    if (i < NN) {
      kk = ((unsigned long long)tkey(es[b * NN + i]) << 32) | (unsigned)i;
    } else {
      kk = (0xFF800000ull << 32) | (unsigned)i;  // +INF pad
    }
    keys[i] = kk;
  }
  __syncthreads();
  int i0 = tid * 2;
  // k=2 stage (j=1), local
  {
    unsigned long long q0 = keys[i0], q1 = keys[i0 + 1];
    CEX(q0, q1, (i0 & 2) == 0);
    keys[i0] = q0; keys[i0 + 1] = q1;
  }
  __syncthreads();
  for (int k = 4; k <= NP; k <<= 1) {
    for (int j = k >> 1; j >= 2; j >>= 1) {
      int i = ((tid & ~(j - 1)) << 1) | (tid & (j - 1));
      int ixj = i | j;
      bool up = ((i & k) == 0);
      unsigned long long a = keys[i], c = keys[ixj];
      if ((a > c) == up) { keys[i] = c; keys[ixj] = a; }
      __syncthreads();
    }
    {
      unsigned long long q0 = keys[i0], q1 = keys[i0 + 1];
      CEX(q0, q1, (i0 & k) == 0);
      keys[i0] = q0; keys[i0 + 1] = q1;
    }
    __syncthreads();
  }
  // extract sorted s -> e1/e2/perm; thread-local pair for scan
  float2 f0 = make_float2(0.f, 0.f), f1 = make_float2(0.f, 0.f);
  {
    unsigned long long k0 = keys[i0], k1 = keys[i0 + 1];
    if (i0 < NN) {
      unsigned m = (unsigned)(k0 >> 32);
      unsigned u = (m & 0x80000000u) ? (m ^ 0x80000000u) : ~m;
      float s = __uint_as_float(u);
      f0.x = __expf(s);
      f0.y = __expf(0.2f * s);
      e1s[b * NN + i0] = f0.x;
      e2s[b * NN + i0] = f0.y;
      perm[b * NN + i0] = (int)(unsigned)k0;
    }
    if (i0 + 1 < NN) {
      unsigned m = (unsigned)(k1 >> 32);
      unsigned u = (m & 0x80000000u) ? (m ^ 0x80000000u) : ~m;
      float s = __uint_as_float(u);
      f1.x = __expf(s);
      f1.y = __expf(0.2f * s);
      e1s[b * NN + i0 + 1] = f1.x;
      e2s[b * NN + i0 + 1] = f1.y;
      perm[b * NN + i0 + 1] = (int)(unsigned)k1;
    }
  }
  // hierarchical inclusive scan of (e1,e2)
  int lane = tid & 63, wid = tid >> 6;
  float tx = f0.x + f1.x, ty = f0.y + f1.y;
  float ix = tx, iy = ty;
#pragma unroll
  for (int dlt = 1; dlt < 64; dlt <<= 1) {
    float ox = __shfl_up(ix, dlt, 64);
    float oy = __shfl_up(iy, dlt, 64);
    if (lane >= dlt) { ix += ox; iy += oy; }
  }
  if (lane == 63) wtot[wid] = make_float2(ix, iy);
  __syncthreads();
  float bx = 0.f, by = 0.f;
#pragma unroll
  for (int ww = 0; ww < 8; ++ww) {
    if (ww < wid) {
      float2 t = wtot[ww];
      bx += t.x;
      by += t.y;
    }
  }
  float ex = bx + ix - tx, ey = by + iy - ty;  // exclusive at i0
  float in0x = ex + f0.x, in0y = ey + f0.y;
  sc[i0] = make_float2(in0x, in0y);
  sc[i0 + 1] = make_float2(in0x + f1.x, in0y + f1.y);
  __syncthreads();
  float s1tot = sc[NN - 1].x;
  // per-target coefficients (2 iters)
  for (int i = tid; i < NN; i += 512) {
    float di = ed[b * NN + i];
    unsigned tt = tkey(-di);
    int lo = 0, hi = NP;
    while (lo < hi) {
      int mid = (lo + hi) >> 1;
      if ((unsigned)(keys[mid] >> 32) <= tt) lo = mid + 1; else hi = mid;
    }
    int k = lo;  // #{s_j <= t_i} <= NN (pads are +INF)
    float p1 = (k > 0) ? sc[k - 1].x : 0.f;
    float p2 = (k > 0) ? sc[k - 1].y : 0.f;
    float Ed = __expf(di);
    float Ed2 = __expf(0.2f * di);
    float den = fmaf(Ed, s1tot - p1, Ed2 * p2);
    kcut[b * NN + i] = k;
    alpha[b * NN + i] = Ed / den;
    beta[b * NN + i] = Ed2 / den;
  }
}

// ---------------------------------------------------------------------------
// Fused chunk-sums + exclusive chunk-prefix. grid (NB, 2): block owns a 64-dim
// slice of one batch. Phase 1: 4 chunk-lanes x 64 dims compute per-chunk
// weighted sums straight into LDS. Phase 2: serial prefix in LDS (128 thr:
// 64 dims x {C1,C2}). Phase 3: coalesced store of exclusive prefix + totals.
// ---------------------------------------------------------------------------
__global__ __launch_bounds__(256) void k_cpfx(
    const unsigned short* __restrict__ hb, const float* __restrict__ e1s,
    const float* __restrict__ e2s, const int* __restrict__ perm,
    float* __restrict__ C1, float* __restrict__ C2) {
  __shared__ float s1[NC + 1][64];
  __shared__ float s2[NC + 1][64];
  int tid = threadIdx.x, b = blockIdx.x, dq = blockIdx.y;
  int d = tid & 63;
  int cl = tid >> 6;  // chunk lane 0..3
  int dglob = dq * 64 + d;
  for (int c = cl; c < NC; c += 4) {
    float v1 = 0.f, v2 = 0.f;
#pragma unroll
    for (int u = 0; u < CS; ++u) {
      int j = c * CS + u;
      int p = perm[b * NN + j];
      float hv = b2f(hb[((long)b * NN + p) * HD + dglob]);
      v1 = fmaf(e1s[b * NN + j], hv, v1);
      v2 = fmaf(e2s[b * NN + j], hv, v2);
    }
    s1[c][d] = v1;
    s2[c][d] = v2;
  }
  __syncthreads();
  if (tid < 128) {
    int dd = tid & 63;
    if (tid < 64) {
      float r = 0.f;
      for (int c = 0; c < NC; ++c) {
        float v = s1[c][dd];
        s1[c][dd] = r;
        r += v;
      }
      s1[NC][dd] = r;
    } else {
      float r = 0.f;
      for (int c = 0; c < NC; ++c) {
        float v = s2[c][dd];
        s2[c][dd] = r;
        r += v;
      }
      s2[NC][dd] = r;
    }
  }
  __syncthreads();
  long base = (long)b * (NC + 1) * HD + dq * 64;
  for (int i = tid; i < (NC + 1) * 64; i += 256) {
    int c = i >> 6, dd = i & 63;
    C1[base + (long)c * HD + dd] = s1[c][dd];
    C2[base + (long)c * HD + dd] = s2[c][dd];
  }
}

// ---------------------------------------------------------------------------
// out[i] = alpha_i*(T1 - C1[c_i] - partial1) + beta_i*(C2[c_i] + partial2)
// APPLY_BN=true: writes bf16 xb (intermediate); false: writes f32 out.
// ---------------------------------------------------------------------------
template <bool APPLY_BN>
__global__ __launch_bounds__(128) void k_out(
    const unsigned short* __restrict__ hb, const float* __restrict__ C1,
    const float* __restrict__ C2, const float* __restrict__ e1s,
    const float* __restrict__ e2s, const int* __restrict__ perm,
    const int* __restrict__ kcut, const float* __restrict__ alpha,
    const float* __restrict__ beta, const float* __restrict__ bias,
    const float* __restrict__ bng, const float* __restrict__ bnb,
    const float* __restrict__ bnm, const float* __restrict__ bnv,
    float* __restrict__ xo, unsigned short* __restrict__ xbo) {
  int d = threadIdx.x, b = blockIdx.x;
  int i0 = blockIdx.y * 8;
  float T1 = C1[((long)b * (NC + 1) + NC) * HD + d];
  float bs = bias[d];
  float sc = 0.f, sh = 0.f;
  if (APPLY_BN) {
    float g = bng[d], bb = bnb[d], m = bnm[d], v = bnv[d];
    sc = g * rsqrtf(v + BN_EPS);
    sh = bb - m * sc;
  }
  for (int i = i0; i < i0 + 8; ++i) {
    int k = kcut[b * NN + i];
    float al = alpha[b * NN + i], bt = beta[b * NN + i];
    int c = k >> 3;
    float base1 = C1[((long)b * (NC + 1) + c) * HD + d];
    float base2 = C2[((long)b * (NC + 1) + c) * HD + d];
    float p1 = 0.f, p2 = 0.f;
    for (int j = c * CS; j < k; ++j) {
      int p = perm[b * NN + j];
      float hv = b2f(hb[((long)b * NN + p) * HD + d]);
      p1 = fmaf(e1s[b * NN + j], hv, p1);
      p2 = fmaf(e2s[b * NN + j], hv, p2);
    }
    float val = fmaf(al, T1 - base1 - p1, fmaf(bt, base2 + p2, bs));
    long off = ((long)b * NN + i) * HD + d;
    if (APPLY_BN) {
      xbo[off] = f2b(fmaxf(fmaf(val, sc, sh), 0.f));
    } else {
      xo[off] = val;
    }
  }
}

extern "C" void kernel_launch(void* const* d_in, const int* in_sizes, int n_in,
                              void* d_out, int out_size, void* d_ws,
                              size_t ws_size, hipStream_t stream) {
  const float* locs = (const float*)d_in[0];
  const float* le_W0 = (const float*)d_in[1];
  const float* le_b0 = (const float*)d_in[2];
  const float* le_W1 = (const float*)d_in[3];
  const float* le_b1 = (const float*)d_in[4];
  const float* le_bn_g = (const float*)d_in[5];
  const float* le_bn_b = (const float*)d_in[6];
  const float* le_bn_m = (const float*)d_in[7];
  const float* le_bn_v = (const float*)d_in[8];
  const float* le_Wo = (const float*)d_in[9];
  const float* le_bo = (const float*)d_in[10];
  const float* gat_W = (const float*)d_in[11];
  const float* gat_asrc = (const float*)d_in[12];
  const float* gat_adst = (const float*)d_in[13];
  const float* gat_b = (const float*)d_in[14];
  const float* bn_g = (const float*)d_in[15];
  const float* bn_b = (const float*)d_in[16];
  const float* bn_m = (const float*)d_in[17];
  const float* bn_v = (const float*)d_in[18];

  float* out = (float*)d_out;                          // final f32 output
  unsigned short* hb = (unsigned short*)d_ws;          // 8,192,000 bf16
  float* C1 = (float*)(hb + 8192000);                  // 1,032,192 f32
  float* C2 = C1 + 1032192;                            // 1,032,192
  float* es = C2 + 1032192;
  float* ed = es + 64000;
  float* e1s = ed + 64000;
  float* e2s = e1s + 64000;
  float* alpha = e2s + 64000;
  float* beta = alpha + 64000;
  int* perm = (int*)(beta + 64000);
  int* kcut = perm + 64000;
  unsigned short* xb = (unsigned short*)(kcut + 64000);  // 8,192,000 bf16
  unsigned short* WT = xb + 8192000;                      // 49,152 bf16

  k_embed<<<1000, 256, 0, stream>>>(locs, le_W0, le_b0, le_W1, le_b1, le_bn_g,
                                    le_bn_b, le_bn_m, le_bn_v, le_Wo, le_bo,
                                    gat_W, WT, xb);
  for (int l = 0; l < 3; ++l) {
    k_gemm_e<<<1000, 256, 0, stream>>>(xb, WT + l * 16384,
                                       gat_asrc + l * 128, gat_adst + l * 128,
                                       hb, es, ed);
    k_sort<<<NB, 512, 0, stream>>>(es, ed, e1s, e2s, perm, kcut, alpha, beta);
    k_cpfx<<<dim3(NB, 2), 256, 0, stream>>>(hb, e1s, e2s, perm, C1, C2);
    if (l < 2) {
      k_out<true><<<dim3(NB, NC), 128, 0, stream>>>(
          hb, C1, C2, e1s, e2s, perm, kcut, alpha, beta, gat_b + l * 128,
          bn_g + l * 128, bn_b + l * 128, bn_m + l * 128, bn_v + l * 128,
          nullptr, xb);
    } else {
      k_out<false><<<dim3(NB, NC), 128, 0, stream>>>(
          hb, C1, C2, e1s, e2s, perm, kcut, alpha, beta, gat_b + 2 * 128,
          nullptr, nullptr, nullptr, nullptr, out, nullptr);
    }
  }
}